// Round 8
// baseline (212.378 us; speedup 1.0000x reference)
//
#include <hip/hip_runtime.h>
#include <cstdint>
#include <cstddef>

// Shapes fixed by the reference harness.
#define MM 2048
#define KK 4096
#define NN 4096
#define GG 32   // K / 128 groups
#define BM 256  // block tile M
#define BN 128  // block tile N
#define BK 64
#define NKT (KK / BK)   // 64 k-tiles

typedef _Float16 half8_t __attribute__((ext_vector_type(8)));
typedef _Float16 half4_t __attribute__((ext_vector_type(4)));
typedef float f32x4 __attribute__((ext_vector_type(4)));
typedef float f32x16 __attribute__((ext_vector_type(16)));

__device__ __forceinline__ void load_lds16(const void* gptr, void* lptr) {
  // 16B-per-lane direct global->LDS (emits global_load_lds_dwordx4).
  // LDS dest = wave-uniform base + lane*16 (NOT a per-lane scatter).
  __builtin_amdgcn_global_load_lds(
      (const __attribute__((address_space(1))) unsigned int*)gptr,
      (__attribute__((address_space(3))) unsigned int*)lptr, 16, 0, 0);
}

// Merged prep: first MM*KK/4 threads convert A fp32->fp16; the rest dequant
// qweight -> fp16 via w = fma(q, s, -z*s). Block-uniform branch.
#define ACNT (MM * KK / 4)
__global__ void prep_kernel(const float* __restrict__ A, const int* __restrict__ q,
                            const float* __restrict__ scales, const float* __restrict__ zeros,
                            _Float16* __restrict__ Ah, _Float16* __restrict__ Wh) {
  const int i = blockIdx.x * blockDim.x + threadIdx.x;
  if (i < ACNT) {
    const float4 v = ((const float4*)A)[i];
    half4_t h;
    h[0] = (_Float16)v.x; h[1] = (_Float16)v.y; h[2] = (_Float16)v.z; h[3] = (_Float16)v.w;
    *(half4_t*)(Ah + 4 * (size_t)i) = h;
  } else {
    const int j = i - ACNT;
    const int e = j << 2;
    const int n = e >> 12;
    const int k = e & (KK - 1);
    const int g = k >> 7;
    const float sc = scales[(n << 5) + g];
    const float zp = zeros[(n << 5) + g];
    const float nzs = -zp * sc;
    const int4 qv = ((const int4*)q)[j];
    half4_t h;
    h[0] = (_Float16)fmaf((float)qv.x, sc, nzs);
    h[1] = (_Float16)fmaf((float)qv.y, sc, nzs);
    h[2] = (_Float16)fmaf((float)qv.z, sc, nzs);
    h[3] = (_Float16)fmaf((float)qv.w, sc, nzs);
    *(half4_t*)(Wh + (size_t)e) = h;
  }
}

// ---------------------------------------------------------------------------
// Pipelined BT-GEMM, R8: 32x32x16 MFMA + 4x2 wave tile to cut LDS-read
// traffic per FLOP 2.67x vs R7 (the measured bottleneck).
// 512 threads = 4 compute waves (128x64 tile each = 4x2 of 32x32x16 f16)
//             + 4 producer waves (global_load_lds width=16 staging).
// Block tile 256x128; grid 8x32 = 256 blocks = 1 per CU.
// LDS: double-buffered sA[2][256*64] + sB[2][128*64] = 96 KB (static LDS
// >64KB verified working in R7 at 66048 B; gfx950 cap is 160 KB).
// Sync protocol identical to R7 (proven): monotone LDS counters, no
// block-wide barrier in the K-loop.
// LDS layout: row-major [rows][64] fp16; 16B-chunk XOR-swizzled with (row&7).
// Frag reads (32 rows/frag): phys chunk = (ks*2 + lane>>5) ^ (lane&7) ->
// each bank-quad hit exactly 8x per wave64 = b128 minimum = conflict-free.
// A-operand layout for 32x32x16: A[m=lane&31][k=(lane>>5)*8 + j]  (analog of
// the verified 16x16x32 layout). C/D: col=lane&31,
// row=(reg&3)+8*(reg>>2)+4*(lane>>5)  (guide-verified, m74/m101).
// ---------------------------------------------------------------------------
__global__ __launch_bounds__(512, 2)
void gemm_pipe(const _Float16* __restrict__ Ah, const _Float16* __restrict__ Wh,
               const float* __restrict__ bias, float* __restrict__ out)
{
  __shared__ __align__(16) _Float16 sA[2][BM * BK];
  __shared__ __align__(16) _Float16 sB[2][BN * BK];
  __shared__ int flg[4];   // [0]=ready b0, [1]=ready b1, [2]=done b0, [3]=done b1

  const int tid = threadIdx.x;
  const int lane = tid & 63;
  const int wave = tid >> 6;    // 0..7

  if (tid == 0) { flg[0] = 0; flg[1] = 0; flg[2] = 0; flg[3] = 0; }
  __syncthreads();              // the only block-wide barrier

  // XCD-aware tile mapping: XCD (bid&7) owns 4 n-tiles -> its W slice
  // (512 rows x 4096 x 2B = 4 MB) fits the per-XCD L2.
  const int bid = blockIdx.x;
  const int xcd = bid & 7;
  const int slot = bid >> 3;            // 0..31
  const int m0 = (slot >> 2) * BM;      // 8 m-tiles
  const int n0 = (xcd * 4 + (slot & 3)) * BN;  // 32 n-tiles

  if (wave >= 4) {
    // ---- producer waves: stage 48 KB/tile = 48 x 1KB chunks, 12 each ----
    const int pw = wave - 4;            // 0..3
    const int srow = lane >> 3;         // 0..7
    const int scc = lane & 7;           // physical 16B chunk
    const int gchunk = scc ^ srow;      // XOR swizzle (row&7 == srow)
    for (int t = 0; t < NKT; ++t) {
      const int bf = t & 1;
      const int k0 = t * BK;
      const int need = 4 * (t >> 1);    // tile t-2 fully consumed
      while (__hip_atomic_load(&flg[2 + bf], __ATOMIC_ACQUIRE,
                               __HIP_MEMORY_SCOPE_WORKGROUP) < need)
        __builtin_amdgcn_s_sleep(1);
#pragma unroll
      for (int i = 0; i < 8; ++i) {     // A: 32 chunks / 4 producers
        const int c = pw + i * 4;       // wave-uniform
        const int row = c * 8 + srow;
        load_lds16(Ah + (size_t)(m0 + row) * KK + k0 + gchunk * 8, (void*)&sA[bf][c * 512]);
      }
#pragma unroll
      for (int i = 0; i < 4; ++i) {     // B: 16 chunks / 4 producers
        const int c = pw + i * 4;
        const int row = c * 8 + srow;
        load_lds16(Wh + (size_t)(n0 + row) * KK + k0 + gchunk * 8, (void*)&sB[bf][c * 512]);
      }
      __builtin_amdgcn_s_waitcnt(0x0f70);   // vmcnt(0) — this wave's loads only
      if (lane == 0)
        __hip_atomic_fetch_add(&flg[bf], 1, __ATOMIC_RELEASE,
                               __HIP_MEMORY_SCOPE_WORKGROUP);
    }
    return;   // producers exit; no barriers below
  }

  // ---- compute waves ----
  const int wm = wave >> 1;       // 0..1 -> m-offset wm*128
  const int wn = wave & 1;        // 0..1 -> n-offset wn*64
  const int col = lane & 31;      // m (A-frag) / n (B-frag)
  const int khalf = lane >> 5;    // 0..1 -> k-half within K=16
  const int l7 = lane & 7;        // == row&7 for all frag rows

  f32x16 acc[4][2];
#pragma unroll
  for (int i = 0; i < 4; ++i)
#pragma unroll
    for (int j = 0; j < 2; ++j)
#pragma unroll
      for (int r = 0; r < 16; ++r) acc[i][j][r] = 0.f;

  for (int t = 0; t < NKT; ++t) {
    const int bf = t & 1;
    const int need = 4 * ((t >> 1) + 1);   // tile t fully staged
    while (__hip_atomic_load(&flg[bf], __ATOMIC_ACQUIRE,
                             __HIP_MEMORY_SCOPE_WORKGROUP) < need)
      __builtin_amdgcn_s_sleep(1);
#pragma unroll
    for (int ks = 0; ks < 4; ++ks) {       // BK=64 = 4 x K16
      const int c = ks * 2 + khalf;        // logical 16B k-chunk
      half8_t a[4], fb[2];
#pragma unroll
      for (int mi = 0; mi < 4; ++mi) {
        const int row = wm * 128 + mi * 32 + col;
        a[mi] = *(const half8_t*)&sA[bf][row * 64 + ((c ^ l7) * 8)];
      }
#pragma unroll
      for (int ni = 0; ni < 2; ++ni) {
        const int row = wn * 64 + ni * 32 + col;
        fb[ni] = *(const half8_t*)&sB[bf][row * 64 + ((c ^ l7) * 8)];
      }
#pragma unroll
      for (int mi = 0; mi < 4; ++mi)
#pragma unroll
        for (int ni = 0; ni < 2; ++ni)
          acc[mi][ni] = __builtin_amdgcn_mfma_f32_32x32x16_f16(a[mi], fb[ni], acc[mi][ni], 0, 0, 0);
    }
    __builtin_amdgcn_s_waitcnt(0xc07f);   // lgkmcnt(0) — frag reads complete
    if (lane == 0)
      __hip_atomic_fetch_add(&flg[2 + bf], 1, __ATOMIC_RELEASE,
                             __HIP_MEMORY_SCOPE_WORKGROUP);
  }

  // Epilogue. 32x32 C/D: col=lane&31, row=(reg&3)+8*(reg>>2)+4*(lane>>5).
#pragma unroll
  for (int ni = 0; ni < 2; ++ni) {
    const int n = n0 + wn * 64 + ni * 32 + col;
    const float bv = bias[n];
#pragma unroll
    for (int mi = 0; mi < 4; ++mi) {
      const int mb = m0 + wm * 128 + mi * 32 + 4 * khalf;
#pragma unroll
      for (int r = 0; r < 16; ++r) {
        const int mrow = mb + (r & 3) + 8 * (r >> 2);
        out[(size_t)mrow * NN + n] = acc[mi][ni][r] + bv;
      }
    }
  }
}

// Fallback (ws too small): fused register-staging GEMM, 256 threads,
// 128x128 tile, 16x16x32 MFMA. Known-correct (R4-R7 family).
__global__ __launch_bounds__(256, 2)
void gemm_fused(const float* __restrict__ Af, const int* __restrict__ qw,
                const float* __restrict__ scales, const float* __restrict__ zeros,
                const float* __restrict__ bias, float* __restrict__ out)
{
  __shared__ __align__(16) _Float16 sA[128 * BK];
  __shared__ __align__(16) _Float16 sB[128 * BK];
  const int tid = threadIdx.x;
  const int lane = tid & 63;
  const int wave = tid >> 6;
  const int wr = wave >> 1, wc = wave & 1;
  const int m0 = (blockIdx.x >> 5) * 128;
  const int n0 = (blockIdx.x & 31) * 128;
  const int lr = lane & 15, quad = lane >> 4;
  f32x4 acc[4][4];
#pragma unroll
  for (int i = 0; i < 4; ++i)
#pragma unroll
    for (int j = 0; j < 4; ++j) acc[i][j] = (f32x4){0.f, 0.f, 0.f, 0.f};
  const int frow = tid >> 4;
  const int fc4 = tid & 15;
  for (int kt = 0; kt < NKT; ++kt) {
    const int k0 = kt * BK;
    const int g = k0 >> 7;
#pragma unroll
    for (int p = 0; p < 8; ++p) {
      const int row = p * 16 + frow;
      const int pc = (fc4 >> 1) ^ (row & 7);
      const int dst = row * 64 + pc * 8 + (fc4 & 1) * 4;
      const float4 avf = *(const float4*)&Af[(size_t)(m0 + row) * KK + k0 + fc4 * 4];
      half4_t ah;
      ah[0] = (_Float16)avf.x; ah[1] = (_Float16)avf.y;
      ah[2] = (_Float16)avf.z; ah[3] = (_Float16)avf.w;
      *(half4_t*)&sA[dst] = ah;
      const int n = n0 + row;
      const float sc = scales[(n << 5) + g];
      const float zp = zeros[(n << 5) + g];
      const float nzs = -zp * sc;
      const int4 qv = *(const int4*)&qw[(size_t)n * KK + k0 + fc4 * 4];
      half4_t bh;
      bh[0] = (_Float16)fmaf((float)qv.x, sc, nzs);
      bh[1] = (_Float16)fmaf((float)qv.y, sc, nzs);
      bh[2] = (_Float16)fmaf((float)qv.z, sc, nzs);
      bh[3] = (_Float16)fmaf((float)qv.w, sc, nzs);
      *(half4_t*)&sB[dst] = bh;
    }
    __syncthreads();
#pragma unroll
    for (int ks = 0; ks < 2; ++ks) {
      half8_t a[4], bfr[4];
#pragma unroll
      for (int tt = 0; tt < 4; ++tt) {
        const int rA = wr * 64 + tt * 16 + lr;
        const int j = ks * 4 + quad;
        a[tt] = *(const half8_t*)&sA[rA * 64 + ((j ^ (lr & 7)) * 8)];
        const int rB = wc * 64 + tt * 16 + lr;
        bfr[tt] = *(const half8_t*)&sB[rB * 64 + ((j ^ (lr & 7)) * 8)];
      }
#pragma unroll
      for (int mi = 0; mi < 4; ++mi)
#pragma unroll
        for (int ni = 0; ni < 4; ++ni)
          acc[mi][ni] = __builtin_amdgcn_mfma_f32_16x16x32_f16(a[mi], bfr[ni], acc[mi][ni], 0, 0, 0);
    }
    __syncthreads();
  }
#pragma unroll
  for (int ni = 0; ni < 4; ++ni) {
    const int n = n0 + wc * 64 + ni * 16 + lr;
    const float bv = bias[n];
#pragma unroll
    for (int mi = 0; mi < 4; ++mi) {
      const int mbase = m0 + wr * 64 + mi * 16 + quad * 4;
#pragma unroll
      for (int r = 0; r < 4; ++r)
        out[(size_t)(mbase + r) * NN + n] = acc[mi][ni][r] + bv;
    }
  }
}

extern "C" void kernel_launch(void* const* d_in, const int* in_sizes, int n_in,
                              void* d_out, int out_size, void* d_ws, size_t ws_size,
                              hipStream_t stream) {
  (void)in_sizes; (void)n_in; (void)out_size;
  const float* A      = (const float*)d_in[0];
  const int*   qw     = (const int*)d_in[1];
  const float* scales = (const float*)d_in[2];
  const float* zeros  = (const float*)d_in[3];
  const float* bias   = (const float*)d_in[4];
  float* out = (float*)d_out;

  const size_t needA = (size_t)MM * KK * sizeof(_Float16);  // 16 MB
  const size_t needW = (size_t)NN * KK * sizeof(_Float16);  // 32 MB

  if (ws_size >= needA + needW) {
    _Float16* Ah = (_Float16*)d_ws;
    _Float16* Wh = (_Float16*)((char*)d_ws + needA);
    prep_kernel<<<((MM + NN) * KK / 4) / 256, 256, 0, stream>>>(A, qw, scales, zeros, Ah, Wh);
    gemm_pipe<<<dim3((MM / BM) * (NN / BN)), dim3(512), 0, stream>>>(Ah, Wh, bias, out);
  } else {
    gemm_fused<<<dim3(512), dim3(256), 0, stream>>>(A, qw, scales, zeros, bias, out);
  }
}

// Round 9
// 207.882 us; speedup vs baseline: 1.0216x; 1.0216x over previous
//
#include <hip/hip_runtime.h>
#include <cstdint>
#include <cstddef>

// Shapes fixed by the reference harness.
#define MM 2048
#define KK 4096
#define NN 4096
#define GG 32   // K / 128 groups
#define BM 256  // block tile M
#define BN 128  // block tile N
#define BK 64
#define NKT (KK / BK)   // 64 k-tiles

typedef _Float16 half8_t __attribute__((ext_vector_type(8)));
typedef _Float16 half4_t __attribute__((ext_vector_type(4)));
typedef float f32x4 __attribute__((ext_vector_type(4)));

__device__ __forceinline__ void load_lds16(const void* gptr, void* lptr) {
  // 16B-per-lane direct global->LDS (emits global_load_lds_dwordx4).
  // LDS dest = wave-uniform base + lane*16 (NOT a per-lane scatter).
  __builtin_amdgcn_global_load_lds(
      (const __attribute__((address_space(1))) unsigned int*)gptr,
      (__attribute__((address_space(3))) unsigned int*)lptr, 16, 0, 0);
}

// Merged prep: first MM*KK/4 threads convert A fp32->fp16; the rest dequant
// qweight -> fp16 via w = fma(q, s, -z*s). Block-uniform branch.
#define ACNT (MM * KK / 4)
__global__ void prep_kernel(const float* __restrict__ A, const int* __restrict__ q,
                            const float* __restrict__ scales, const float* __restrict__ zeros,
                            _Float16* __restrict__ Ah, _Float16* __restrict__ Wh) {
  const int i = blockIdx.x * blockDim.x + threadIdx.x;
  if (i < ACNT) {
    const float4 v = ((const float4*)A)[i];
    half4_t h;
    h[0] = (_Float16)v.x; h[1] = (_Float16)v.y; h[2] = (_Float16)v.z; h[3] = (_Float16)v.w;
    *(half4_t*)(Ah + 4 * (size_t)i) = h;
  } else {
    const int j = i - ACNT;
    const int e = j << 2;
    const int n = e >> 12;
    const int k = e & (KK - 1);
    const int g = k >> 7;
    const float sc = scales[(n << 5) + g];
    const float zp = zeros[(n << 5) + g];
    const float nzs = -zp * sc;
    const int4 qv = ((const int4*)q)[j];
    half4_t h;
    h[0] = (_Float16)fmaf((float)qv.x, sc, nzs);
    h[1] = (_Float16)fmaf((float)qv.y, sc, nzs);
    h[2] = (_Float16)fmaf((float)qv.z, sc, nzs);
    h[3] = (_Float16)fmaf((float)qv.w, sc, nzs);
    *(half4_t*)(Wh + (size_t)e) = h;
  }
}

// ---------------------------------------------------------------------------
// Pipelined BT-GEMM, R9: R7's proven conflict-free 16x16x32 frag geometry,
// wave tile enlarged 64x64 -> 128x64 (0.375 LDS reads/MFMA vs 0.5).
// R8 post-mortem: 32x32 frags span 32 LDS rows (4KB) per ds_read_b128 ->
// +4 conflict-cycles per read (6.29M total). R9 reads are instruction-
// identical to R7 (16-row span, chunk XOR (lane&7)) -> expect 0 conflicts.
// 512 threads = 4 compute waves (128x64 = 8x4 of 16x16x32 f16 MFMA, acc
// 128 AGPR) + 4 producer waves (global_load_lds width=16).
// Block tile 256x128; grid 8x32 = 256 blocks = 1 per CU; LDS 96KB dbuf.
// Sync protocol identical to R7/R8 (proven): monotone LDS counters, no
// block-wide barrier in the K-loop.
// ---------------------------------------------------------------------------
__global__ __launch_bounds__(512, 2)
void gemm_pipe(const _Float16* __restrict__ Ah, const _Float16* __restrict__ Wh,
               const float* __restrict__ bias, float* __restrict__ out)
{
  __shared__ __align__(16) _Float16 sA[2][BM * BK];
  __shared__ __align__(16) _Float16 sB[2][BN * BK];
  __shared__ int flg[4];   // [0]=ready b0, [1]=ready b1, [2]=done b0, [3]=done b1

  const int tid = threadIdx.x;
  const int lane = tid & 63;
  const int wave = tid >> 6;    // 0..7

  if (tid == 0) { flg[0] = 0; flg[1] = 0; flg[2] = 0; flg[3] = 0; }
  __syncthreads();              // the only block-wide barrier

  // XCD-aware tile mapping: XCD (bid&7) owns 4 n-tiles.
  const int bid = blockIdx.x;
  const int xcd = bid & 7;
  const int slot = bid >> 3;            // 0..31
  const int m0 = (slot >> 2) * BM;      // 8 m-tiles
  const int n0 = (xcd * 4 + (slot & 3)) * BN;  // 32 n-tiles

  if (wave >= 4) {
    // ---- producer waves: stage 48 KB/tile = 48 x 1KB chunks, 12 each ----
    const int pw = wave - 4;            // 0..3
    const int srow = lane >> 3;         // 0..7
    const int scc = lane & 7;           // physical 16B chunk
    const int gchunk = scc ^ srow;      // XOR swizzle (row&7 == srow)
    for (int t = 0; t < NKT; ++t) {
      const int bf = t & 1;
      const int k0 = t * BK;
      const int need = 4 * (t >> 1);    // tile t-2 fully consumed
      while (__hip_atomic_load(&flg[2 + bf], __ATOMIC_ACQUIRE,
                               __HIP_MEMORY_SCOPE_WORKGROUP) < need)
        __builtin_amdgcn_s_sleep(1);
#pragma unroll
      for (int i = 0; i < 8; ++i) {     // A: 32 chunks / 4 producers
        const int c = pw + i * 4;       // wave-uniform
        const int row = c * 8 + srow;
        load_lds16(Ah + (size_t)(m0 + row) * KK + k0 + gchunk * 8, (void*)&sA[bf][c * 512]);
      }
#pragma unroll
      for (int i = 0; i < 4; ++i) {     // B: 16 chunks / 4 producers
        const int c = pw + i * 4;
        const int row = c * 8 + srow;
        load_lds16(Wh + (size_t)(n0 + row) * KK + k0 + gchunk * 8, (void*)&sB[bf][c * 512]);
      }
      __builtin_amdgcn_s_waitcnt(0x0f70);   // vmcnt(0) — this wave's loads only
      if (lane == 0)
        __hip_atomic_fetch_add(&flg[bf], 1, __ATOMIC_RELEASE,
                               __HIP_MEMORY_SCOPE_WORKGROUP);
    }
    return;   // producers exit; no barriers below
  }

  // ---- compute waves: 128x64 tile = 8x4 of 16x16x32 ----
  const int wm = wave >> 1;       // 0..1 -> m-offset wm*128
  const int wn = wave & 1;        // 0..1 -> n-offset wn*64
  const int lr = lane & 15, quad = lane >> 4;

  f32x4 acc[8][4];
#pragma unroll
  for (int i = 0; i < 8; ++i)
#pragma unroll
    for (int j = 0; j < 4; ++j) acc[i][j] = (f32x4){0.f, 0.f, 0.f, 0.f};

  for (int t = 0; t < NKT; ++t) {
    const int bf = t & 1;
    const int need = 4 * ((t >> 1) + 1);   // tile t fully staged
    while (__hip_atomic_load(&flg[bf], __ATOMIC_ACQUIRE,
                             __HIP_MEMORY_SCOPE_WORKGROUP) < need)
      __builtin_amdgcn_s_sleep(1);
#pragma unroll
    for (int ks = 0; ks < 2; ++ks) {
      const int j = ks * 4 + quad;
      const int co = (j ^ (lr & 7)) * 8;   // swizzled 16B chunk offset
      half8_t a[8], fb[4];
#pragma unroll
      for (int tt = 0; tt < 8; ++tt) {
        const int rA = wm * 128 + tt * 16 + lr;   // 16-row span per read
        a[tt] = *(const half8_t*)&sA[bf][rA * 64 + co];
      }
#pragma unroll
      for (int ni = 0; ni < 4; ++ni) {
        const int rB = wn * 64 + ni * 16 + lr;
        fb[ni] = *(const half8_t*)&sB[bf][rB * 64 + co];
      }
#pragma unroll
      for (int mi = 0; mi < 8; ++mi)
#pragma unroll
        for (int ni = 0; ni < 4; ++ni)
          acc[mi][ni] = __builtin_amdgcn_mfma_f32_16x16x32_f16(a[mi], fb[ni], acc[mi][ni], 0, 0, 0);
    }
    __builtin_amdgcn_s_waitcnt(0xc07f);   // lgkmcnt(0) — frag reads complete
    if (lane == 0)
      __hip_atomic_fetch_add(&flg[2 + bf], 1, __ATOMIC_RELEASE,
                             __HIP_MEMORY_SCOPE_WORKGROUP);
  }

  // Epilogue. C/D layout: col = lane&15, row = quad*4 + reg.
#pragma unroll
  for (int ni = 0; ni < 4; ++ni) {
    const int n = n0 + wn * 64 + ni * 16 + lr;
    const float bv = bias[n];
#pragma unroll
    for (int mi = 0; mi < 8; ++mi) {
      const int mbase = m0 + wm * 128 + mi * 16 + quad * 4;
#pragma unroll
      for (int r = 0; r < 4; ++r)
        out[(size_t)(mbase + r) * NN + n] = acc[mi][ni][r] + bv;
    }
  }
}

// Fallback (ws too small): fused register-staging GEMM, 256 threads,
// 128x128 tile, 16x16x32 MFMA. Known-correct (R4-R7 family).
__global__ __launch_bounds__(256, 2)
void gemm_fused(const float* __restrict__ Af, const int* __restrict__ qw,
                const float* __restrict__ scales, const float* __restrict__ zeros,
                const float* __restrict__ bias, float* __restrict__ out)
{
  __shared__ __align__(16) _Float16 sA[128 * BK];
  __shared__ __align__(16) _Float16 sB[128 * BK];
  const int tid = threadIdx.x;
  const int lane = tid & 63;
  const int wave = tid >> 6;
  const int wr = wave >> 1, wc = wave & 1;
  const int m0 = (blockIdx.x >> 5) * 128;
  const int n0 = (blockIdx.x & 31) * 128;
  const int lr = lane & 15, quad = lane >> 4;
  f32x4 acc[4][4];
#pragma unroll
  for (int i = 0; i < 4; ++i)
#pragma unroll
    for (int j = 0; j < 4; ++j) acc[i][j] = (f32x4){0.f, 0.f, 0.f, 0.f};
  const int frow = tid >> 4;
  const int fc4 = tid & 15;
  for (int kt = 0; kt < NKT; ++kt) {
    const int k0 = kt * BK;
    const int g = k0 >> 7;
#pragma unroll
    for (int p = 0; p < 8; ++p) {
      const int row = p * 16 + frow;
      const int pc = (fc4 >> 1) ^ (row & 7);
      const int dst = row * 64 + pc * 8 + (fc4 & 1) * 4;
      const float4 avf = *(const float4*)&Af[(size_t)(m0 + row) * KK + k0 + fc4 * 4];
      half4_t ah;
      ah[0] = (_Float16)avf.x; ah[1] = (_Float16)avf.y;
      ah[2] = (_Float16)avf.z; ah[3] = (_Float16)avf.w;
      *(half4_t*)&sA[dst] = ah;
      const int n = n0 + row;
      const float sc = scales[(n << 5) + g];
      const float zp = zeros[(n << 5) + g];
      const float nzs = -zp * sc;
      const int4 qv = *(const int4*)&qw[(size_t)n * KK + k0 + fc4 * 4];
      half4_t bh;
      bh[0] = (_Float16)fmaf((float)qv.x, sc, nzs);
      bh[1] = (_Float16)fmaf((float)qv.y, sc, nzs);
      bh[2] = (_Float16)fmaf((float)qv.z, sc, nzs);
      bh[3] = (_Float16)fmaf((float)qv.w, sc, nzs);
      *(half4_t*)&sB[dst] = bh;
    }
    __syncthreads();
#pragma unroll
    for (int ks = 0; ks < 2; ++ks) {
      half8_t a[4], bfr[4];
#pragma unroll
      for (int tt = 0; tt < 4; ++tt) {
        const int rA = wr * 64 + tt * 16 + lr;
        const int j = ks * 4 + quad;
        a[tt] = *(const half8_t*)&sA[rA * 64 + ((j ^ (lr & 7)) * 8)];
        const int rB = wc * 64 + tt * 16 + lr;
        bfr[tt] = *(const half8_t*)&sB[rB * 64 + ((j ^ (lr & 7)) * 8)];
      }
#pragma unroll
      for (int mi = 0; mi < 4; ++mi)
#pragma unroll
        for (int ni = 0; ni < 4; ++ni)
          acc[mi][ni] = __builtin_amdgcn_mfma_f32_16x16x32_f16(a[mi], bfr[ni], acc[mi][ni], 0, 0, 0);
    }
    __syncthreads();
  }
#pragma unroll
  for (int ni = 0; ni < 4; ++ni) {
    const int n = n0 + wc * 64 + ni * 16 + lr;
    const float bv = bias[n];
#pragma unroll
    for (int mi = 0; mi < 4; ++mi) {
      const int mbase = m0 + wr * 64 + mi * 16 + quad * 4;
#pragma unroll
      for (int r = 0; r < 4; ++r)
        out[(size_t)(mbase + r) * NN + n] = acc[mi][ni][r] + bv;
    }
  }
}

extern "C" void kernel_launch(void* const* d_in, const int* in_sizes, int n_in,
                              void* d_out, int out_size, void* d_ws, size_t ws_size,
                              hipStream_t stream) {
  (void)in_sizes; (void)n_in; (void)out_size;
  const float* A      = (const float*)d_in[0];
  const int*   qw     = (const int*)d_in[1];
  const float* scales = (const float*)d_in[2];
  const float* zeros  = (const float*)d_in[3];
  const float* bias   = (const float*)d_in[4];
  float* out = (float*)d_out;

  const size_t needA = (size_t)MM * KK * sizeof(_Float16);  // 16 MB
  const size_t needW = (size_t)NN * KK * sizeof(_Float16);  // 32 MB

  if (ws_size >= needA + needW) {
    _Float16* Ah = (_Float16*)d_ws;
    _Float16* Wh = (_Float16*)((char*)d_ws + needA);
    prep_kernel<<<((MM + NN) * KK / 4) / 256, 256, 0, stream>>>(A, qw, scales, zeros, Ah, Wh);
    gemm_pipe<<<dim3((MM / BM) * (NN / BN)), dim3(512), 0, stream>>>(Ah, Wh, bias, out);
  } else {
    gemm_fused<<<dim3(512), dim3(256), 0, stream>>>(A, qw, scales, zeros, bias, out);
  }
}